// Round 15
// baseline (121.765 us; speedup 1.0000x reference)
//
#include <hip/hip_runtime.h>

#define T_LEN 2048
#define CH 64
#define NH 8
#define STILE 64      // keys per block-iteration (2 half-phases of 32 per wave)
#define TTILE 256     // queries per block (8 waves x 32)
#define WT 32         // queries per wave
#define NIT (T_LEN / STILE)   // 32
#define KSZ (STILE * CH)      // k_hi elems per buffer (64x64, no pad, XOR-swizzled)
#define CS 72         // v_s row stride (bf16), 16B-aligned rows (b128-safe)
#define QS 260        // f32 t-stride for Q staging (16B-aligned rows)

// scale = ch^-0.5 (=1/8) * log2(e), folded into Q; softmax uses exp2 directly.
#define QSCALE 0.180336880972948929f

typedef __attribute__((ext_vector_type(4))) float  f32x4;
typedef __attribute__((ext_vector_type(8))) __bf16 bf16x8;
typedef __attribute__((ext_vector_type(4))) __bf16 bf16x4;
typedef __attribute__((ext_vector_type(2))) __bf16 bf16x2;
typedef __attribute__((ext_vector_type(2))) unsigned int uint2v;
typedef __attribute__((ext_vector_type(4))) unsigned int uint4v;

union SMem {
  float qstage[CH * QS];                  // 66560 B (pre-loop only)
  struct {
    __bf16 k_hi[2][KSZ];                  // 2 x 8192 B  (K^T, XOR-swizzled rows)
    __bf16 v_s [2][CH * CS];              // 2 x 9216 B  (V, double-buffered)
  } loop;                                 // 34816 B; union max = 66560 B
};

#define MFMA(A, B, C) __builtin_amdgcn_mfma_f32_16x16x32_bf16((A), (B), (C), 0, 0, 0)

// pack two f32 -> one u32 of 2 bf16 (v_cvt_pk_bf16_f32)
__device__ __forceinline__ unsigned pkbf2(float lo, float hi) {
  bf16x2 t = {(__bf16)lo, (__bf16)hi};
  return __builtin_bit_cast(unsigned, t);
}

// ---- K staging (512 threads): thread -> (s = tid&63, cg = tid>>6).
// Swizzle: elem ^= ((s&7)<<3). Store slot = cg^(s&7); read slot =
// (4kb+quad)^(tn&7) -> both minimum-round conflict-free (verified R11).
__device__ __forceinline__ void load_k8(const float* kp, int s0, int tid, float (&kr)[8]) {
  int s  = tid & 63;                      // key column
  int cg = tid >> 6;                      // channel group 0..7 (== wave)
  const float* kc = kp + (size_t)(8 * cg) * T_LEN + s0 + s;
#pragma unroll
  for (int j = 0; j < 8; ++j)
    kr[j] = kc[(size_t)j * T_LEN];        // 64 lanes read 64 consecutive s: coalesced
}

__device__ __forceinline__ void store_k8(__bf16* kh, int tid, const float (&kr)[8]) {
  int s  = tid & 63;
  int cg = tid >> 6;
  uint4v wv = {pkbf2(kr[0], kr[1]), pkbf2(kr[2], kr[3]),
               pkbf2(kr[4], kr[5]), pkbf2(kr[6], kr[7])};   // 4 packed cvts
  bf16x8 w = __builtin_bit_cast(bf16x8, wv);
  int e = (s << 6) + (cg << 3);
  *(bf16x8*)&kh[e ^ ((s & 7) << 3)] = w;
}

// ---- V staging (512 threads): thread -> (c = tid>>3, s8 = (tid&7)*8).
// Global: 32B contiguous/thread, 8 threads cover a 256B row (coalesced).
// LDS b128 slot = (c + (lane&7)) & 7 -> minimum-round conflict-free (R14).
__device__ __forceinline__ void load_v(const float* vp, int s0, int tid, f32x4 (&vreg)[2]) {
  int c  = tid >> 3;
  int s8 = (tid & 7) << 3;
  const float* vc = vp + (size_t)c * T_LEN + s0 + s8;
  vreg[0] = *(const f32x4*)(vc);
  vreg[1] = *(const f32x4*)(vc + 4);
}

__device__ __forceinline__ void store_v(__bf16* vs, int tid, const f32x4 (&vreg)[2]) {
  int c  = tid >> 3;
  int s8 = (tid & 7) << 3;
  uint4v wv = {pkbf2(vreg[0].x, vreg[0].y), pkbf2(vreg[0].z, vreg[0].w),
               pkbf2(vreg[1].x, vreg[1].y), pkbf2(vreg[1].z, vreg[1].w)};
  *(bf16x8*)&vs[c * CS + s8] = __builtin_bit_cast(bf16x8, wv);
}

// NOTE (journal): the "64-VGPR wall" (R6/R7) is a 1024-thread-block artifact:
// cap = 512/(min_blocks x waves_per_EU). (512,1) -> 256-VGPR budget, and
// grid==256==#CUs forces 1 block/CU anyway. R15: 8-wave full-K-per-wave
// structure (AITER/HK shape): no ws split, no cross-ws epilogue, uniform
// wave workload, 2x ILP/wave. R8/R12: stores stay LATE. R10: ones-MFMA l.
// R11: swizzled K (3.5M conflict = b128 multi-round floor). R13: setprio ~0.
__global__ __launch_bounds__(512, 1)
void qkv_attn_mfma(const float* __restrict__ qkv, float* __restrict__ out) {
  __shared__ SMem sm;
  const int tid  = threadIdx.x;
  const int lane = tid & 63;
  const int wt   = tid >> 6;     // wave 0..7 = t-eighth (32 queries each)
  const int tn   = lane & 15;
  const int quad = lane >> 4;

  // ---- XCD-aware swizzle: 256 blocks, 8 XCDs -> 32-block chunks per XCD.
  const int d0 = blockIdx.x;
  const int w  = ((d0 & 7) << 5) | (d0 >> 3);
  const int ttile = w & 7;                 // 0..7
  const int bh    = w >> 3;                // 0..31
  const int b = bh >> 3, h = bh & 7;
  const size_t base = (size_t)b * (3 * NH * CH) * T_LEN;
  const float* qp = qkv + base + (size_t)(CH * h) * T_LEN;
  const float* kp = qkv + base + (size_t)(CH * (NH + h)) * T_LEN;
  const float* vp = qkv + base + (size_t)(CH * (2 * NH + h)) * T_LEN;
  const int t0 = ttile * TTILE;

  // ---- stage Q tile fp32 [c][t_local]  (64c x 256t = 32 f32/thread)
#pragma unroll
  for (int rr = 0; rr < 8; ++rr) {
    int fidx = rr * 512 + tid;             // f32x4 chunk id, 4096 total
    int c  = fidx >> 6;
    int t4 = (fidx & 63) << 2;
    f32x4 q4 = *(const f32x4*)(qp + (size_t)c * T_LEN + t0 + t4);
    *(f32x4*)&sm.qstage[c * QS + t4] = q4;
  }
  __syncthreads();

  // ---- build Q B-fragments: B[k=c][n=t]
  bf16x8 qh[2][2];                         // [nb][kb]
#pragma unroll
  for (int nb = 0; nb < 2; ++nb)
#pragma unroll
    for (int kb = 0; kb < 2; ++kb) {
      int tloc = wt * WT + nb * 16 + tn;
      bf16x8 H;
#pragma unroll
      for (int j = 0; j < 8; ++j) {
        float qv = sm.qstage[(kb * 32 + quad * 8 + j) * QS + tloc] * QSCALE;
        H[j] = (__bf16)qv;
      }
      qh[nb][kb] = H;
    }
  __syncthreads();   // qstage memory reused by loop arrays below

  f32x4 acc[4][2];                         // O^T: [mbc=c][nb=t] (full-K, no split)
  f32x4 acc_l[2];                          // l via ones-MFMA: [nb] (complete)
#pragma unroll
  for (int mbc = 0; mbc < 4; ++mbc)
#pragma unroll
    for (int nb = 0; nb < 2; ++nb)
      acc[mbc][nb] = (f32x4){0.f, 0.f, 0.f, 0.f};
  acc_l[0] = (f32x4){0.f, 0.f, 0.f, 0.f};
  acc_l[1] = (f32x4){0.f, 0.f, 0.f, 0.f};

  // ones A-fragment: l[t] = sum_s 1 * P[s][t] (every output row = full l)
  bf16x8 av_one;
#pragma unroll
  for (int j = 0; j < 8; ++j) av_one[j] = (__bf16)1.0f;

  // ---- prologue: all threads stage both K and V of tile 0
  float  kreg[8];
  f32x4  vreg[2];
  load_k8(kp, 0, tid, kreg);
  load_v (vp, 0, tid, vreg);
  store_k8(sm.loop.k_hi[0], tid, kreg);
  store_v (sm.loop.v_s[0], tid, vreg);
  __syncthreads();

  for (int it = 0; it < NIT; ++it) {
    const int cur = it & 1;
    const bool more = (it + 1 < NIT);

    // ---- global prefetch of tile it+1 (full body of slack before stores)
    if (more) {
      load_k8(kp, (it + 1) * STILE, tid, kreg);
      load_v (vp, (it + 1) * STILE, tid, vreg);
    }

    const __bf16* kh = sm.loop.k_hi[cur];
    const __bf16* vs = sm.loop.v_s[cur];
    const int swz = (tn & 7) << 3;

    // ---- two 32-key half-phases; each is the proven R5 body.
#pragma unroll
    for (int hh = 0; hh < 2; ++hh) {
      const int sbase = 32 * hh;

      bf16x8 ah[2][2];
#pragma unroll
      for (int mb = 0; mb < 2; ++mb) {
        const int srow = sbase + 16 * mb + tn;          // srow&7 == tn&7
#pragma unroll
        for (int kb = 0; kb < 2; ++kb) {
          int e = (srow << 6) + 32 * kb + 8 * quad;
          ah[mb][kb] = *(const bf16x8*)&kh[e ^ swz];
        }
      }
      __builtin_amdgcn_s_setprio(1);
      f32x4 d[2][2];
#pragma unroll
      for (int mb = 0; mb < 2; ++mb)
#pragma unroll
        for (int nb = 0; nb < 2; ++nb) {
          f32x4 t = (f32x4){0.f, 0.f, 0.f, 0.f};
          t = MFMA(ah[mb][0], qh[nb][0], t);
          t = MFMA(ah[mb][1], qh[nb][1], t);
          d[mb][nb] = t;
        }
      __builtin_amdgcn_s_setprio(0);

      bf16x8 av[4];
#pragma unroll
      for (int mbc = 0; mbc < 4; ++mbc)
        av[mbc] = *(const bf16x8*)&vs[(16 * mbc + tn) * CS + sbase + quad * 8];

      // p = exp2(s'); in-register redistribution to PV B-fragment (verified):
      // lane(q,tn) holds P[s=16mb+4q+r][t=tn] -> needs P[s=8q+j][t=tn].
      bf16x8 bp[2];
#pragma unroll
      for (int nb = 0; nb < 2; ++nb) {
#pragma unroll
        for (int mb = 0; mb < 2; ++mb)
#pragma unroll
          for (int r = 0; r < 4; ++r)
            d[mb][nb][r] = __builtin_amdgcn_exp2f(d[mb][nb][r]);
        unsigned u00 = pkbf2(d[0][nb][0], d[0][nb][1]);
        unsigned u01 = pkbf2(d[0][nb][2], d[0][nb][3]);
        unsigned u10 = pkbf2(d[1][nb][0], d[1][nb][1]);
        unsigned u11 = pkbf2(d[1][nb][2], d[1][nb][3]);
        uint2v s0 = __builtin_amdgcn_permlane32_swap(u00, u10, false, false);
        uint2v r0 = __builtin_amdgcn_permlane16_swap(s0.x, s0.y, false, false);
        uint2v s1 = __builtin_amdgcn_permlane32_swap(u01, u11, false, false);
        uint2v r1 = __builtin_amdgcn_permlane16_swap(s1.x, s1.y, false, false);
        uint4v wv = {r0.x, r1.x, r0.y, r1.y}; // w0,w1,w2,w3 -> j=0..7
        bp[nb] = __builtin_bit_cast(bf16x8, wv);
      }

      __builtin_amdgcn_s_setprio(1);
#pragma unroll
      for (int mbc = 0; mbc < 4; ++mbc)
#pragma unroll
        for (int nb = 0; nb < 2; ++nb)
          acc[mbc][nb] = MFMA(av[mbc], bp[nb], acc[mbc][nb]);
#pragma unroll
      for (int nb = 0; nb < 2; ++nb)
        acc_l[nb] = MFMA(av_one, bp[nb], acc_l[nb]);
      __builtin_amdgcn_s_setprio(0);
    }

    // ---- stage tile it+1 LATE (prefetch had the whole iteration in flight)
    if (more) {
      store_k8(sm.loop.k_hi[cur ^ 1], tid, kreg);
      store_v (sm.loop.v_s [cur ^ 1], tid, vreg);
    }
    __syncthreads();
  }

  // ---- epilogue: no cross-wave reduction needed — each wave owns its 32
  // queries over ALL keys; acc_l rows all equal the complete denominator.
  float* op = out + (size_t)bh * CH * T_LEN;
#pragma unroll
  for (int nb = 0; nb < 2; ++nb) {
    float inv_l = 1.0f / acc_l[nb][0];
    int t = t0 + wt * WT + nb * 16 + tn;
#pragma unroll
    for (int mbc = 0; mbc < 4; ++mbc) {
      f32x4 o = acc[mbc][nb] * inv_l;
      int c = 16 * mbc + quad * 4;
      op[(size_t)(c + 0) * T_LEN + t] = o.x;
      op[(size_t)(c + 1) * T_LEN + t] = o.y;
      op[(size_t)(c + 2) * T_LEN + t] = o.z;
      op[(size_t)(c + 3) * T_LEN + t] = o.w;
    }
  }
}

extern "C" void kernel_launch(void* const* d_in, const int* in_sizes, int n_in,
                              void* d_out, int out_size, void* d_ws, size_t ws_size,
                              hipStream_t stream) {
  const float* qkv = (const float*)d_in[0];
  float* out = (float*)d_out;
  dim3 grid(256);   // 256 blocks of 512 threads (XCD-swizzled in-kernel)
  qkv_attn_mfma<<<grid, 512, 0, stream>>>(qkv, out);
}